// Round 14
// baseline (284.989 us; speedup 1.0000x reference)
//
#include <hip/hip_runtime.h>

#define H 128
#define BSH 10                // bucket shift: 1024 rows per bucket
#define BROWS (1 << BSH)
#define BCAP 18432            // per-bucket edge cap (mean 16384 + ~16 sigma)

typedef __attribute__((ext_vector_type(8))) short bf16x8;
typedef __attribute__((ext_vector_type(4))) float f32x4;
typedef __attribute__((ext_vector_type(2))) float f32x2;
typedef unsigned int uint;
typedef unsigned short ushort;
typedef unsigned char uchar;

__device__ __forceinline__ ushort f2bf(float f) {
    uint u = __builtin_bit_cast(uint, f);
    uint r = u + 0x7FFFu + ((u >> 16) & 1u);
    return (ushort)(r >> 16);
}
__device__ __forceinline__ float bf_lo(uint u) {
    return __builtin_bit_cast(float, u << 16);
}
__device__ __forceinline__ float bf_hi(uint u) {
    return __builtin_bit_cast(float, u & 0xFFFF0000u);
}

// ---- fp8 e4m3 helpers (values >= 0 only; h is post-relu) ----

__device__ __forceinline__ uint fp8_enc1(float v) {
    // v in [0, 448]; round-to-nearest-even to e4m3
    if (v < 0.015625f) {                 // subnormal: multiples of 2^-9
        float r = v * 512.0f;
        uint q = (uint)(r + 0.5f);
        return q > 8u ? 8u : q;
    }
    uint u = __builtin_bit_cast(uint, v);
    u += 0x7FFFFu + ((u >> 20) & 1u);
    int ef = (int)(u >> 23) - 120;       // rebias to e4m3
    uint r = ((uint)ef << 3) | ((u >> 20) & 7u);
    if (ef > 15 || r > 0x7Eu) r = 0x7Eu; // clamp to 448
    return r;
}

__device__ __forceinline__ float2 fp8_dec2(uint v) {
#if __has_builtin(__builtin_amdgcn_cvt_pk_f32_fp8)
    f32x2 r = __builtin_amdgcn_cvt_pk_f32_fp8((int)v, false);
    return make_float2(r[0], r[1]);
#else
    float2 o;
    uint b0 = v & 0xFFu, b1 = (v >> 8) & 0xFFu;
    uint e0 = (b0 >> 3) & 15u, m0 = b0 & 7u;
    uint e1 = (b1 >> 3) & 15u, m1 = b1 & 7u;
    float n0 = __builtin_bit_cast(float, ((e0 + 120u) << 23) | (m0 << 20));
    float n1 = __builtin_bit_cast(float, ((e1 + 120u) << 23) | (m1 << 20));
    o.x = e0 ? n0 : (float)m0 * 0.001953125f;
    o.y = e1 ? n1 : (float)m1 * 0.001953125f;
    return o;
#endif
}

__device__ __forceinline__ uint fp8_enc4(float a, float b, float c, float d) {
#if __has_builtin(__builtin_amdgcn_cvt_pk_fp8_f32)
    int w = 0;
    w = __builtin_amdgcn_cvt_pk_fp8_f32(a, b, w, false);
    w = __builtin_amdgcn_cvt_pk_fp8_f32(c, d, w, true);
    return (uint)w;
#else
    return fp8_enc1(a) | (fp8_enc1(b) << 8) | (fp8_enc1(c) << 16) | (fp8_enc1(d) << 24);
#endif
}

// =======================================================================
// CSR build: fixed-capacity 1024-row buckets (R11-proven), 2 kernels.
// =======================================================================

__global__ void scatter_direct(const int* __restrict__ ei, int E, int NB,
                               int* __restrict__ gcnt, int2* __restrict__ ebuf) {
    __shared__ int cnt[1024];
    __shared__ int base[1024];
    int blk = blockIdx.x, t = threadIdx.x;
    for (int b = t; b < NB; b += 256) cnt[b] = 0;
    __syncthreads();
    int lo = blk << 12, hi = min(lo + 4096, E);
    for (int e = lo + t; e < hi; e += 256) atomicAdd(&cnt[ei[e] >> BSH], 1);
    __syncthreads();
    for (int b = t; b < NB; b += 256) {
        int c = cnt[b];
        base[b] = c ? atomicAdd(&gcnt[b * 16], c) : 0;
        cnt[b] = 0;
    }
    __syncthreads();
    for (int e = lo + t; e < hi; e += 256) {
        int r = ei[e], c = ei[E + e];
        int b = r >> BSH;
        int pos = base[b] + atomicAdd(&cnt[b], 1);
        if (pos < BCAP) ebuf[(size_t)b * BCAP + pos] = make_int2(r, c);
    }
}

__global__ __launch_bounds__(1024)
void bucket_csr2(const int2* __restrict__ ebuf, const int* __restrict__ gcnt,
                 int NB, int N, int* __restrict__ deg, int* __restrict__ off,
                 int* __restrict__ colss) {
    __shared__ int rcnt[BROWS], rloff[BROWS];
    int b = blockIdx.x, t = threadIdx.x;
    int rowbase = b << BSH;
    int ebase = b * BCAP;
    int ne = min(gcnt[b * 16], BCAP);
    rcnt[t] = 0;
    __syncthreads();
    for (int e = t; e < ne; e += 1024) atomicAdd(&rcnt[ebuf[(size_t)ebase + e].x - rowbase], 1);
    __syncthreads();
    int v = rcnt[t];
    rloff[t] = v;
    __syncthreads();
    for (int d = 1; d < BROWS; d <<= 1) {
        int u = (t >= d) ? rloff[t - d] : 0;
        __syncthreads();
        rloff[t] += u;
        __syncthreads();
    }
    int ex = rloff[t] - v;
    int row = rowbase + t;
    if (row < N) {
        deg[row] = v;
        off[row] = ebase + ex;
    }
    __syncthreads();
    rloff[t] = ex;
    rcnt[t] = 0;
    __syncthreads();
    for (int e = t; e < ne; e += 1024) {
        int2 rc = ebuf[(size_t)ebase + e];
        int lr = rc.x - rowbase;
        int pz = atomicAdd(&rcnt[lr], 1);
        colss[ebase + rloff[lr] + pz] = rc.y;
    }
}

// =======================================================================
// cvec: c_i[k] = sum_j W3[i][k][j] * relu(W4[i][j]); one wave per k.
// =======================================================================

__global__ void cvec_kernel(const float* __restrict__ W3, const float* __restrict__ W4,
                            float* __restrict__ cvec) {
    __shared__ float r4[H];
    int i = blockIdx.x, t = threadIdx.x;
    if (t < H) r4[t] = fmaxf(W4[i * H + t], 0.f);
    __syncthreads();
    int wv = t >> 6, l = t & 63;
    for (int k = wv; k < H; k += 4) {
        const float* w3 = W3 + (size_t)i * H * H + (size_t)k * H;
        float s = w3[l] * r4[l] + w3[l + 64] * r4[l + 64];
        for (int d = 1; d < 64; d <<= 1) s += __shfl_xor(s, d);
        if (l == 0) cvec[i * H + k] = s;
    }
}

// casts both weight tensors in one launch (dst W1b, W2b contiguous)
__global__ void cast_w(const float* __restrict__ W1, const float* __restrict__ W2,
                       ushort* __restrict__ outp, int n8) {
    int i = blockIdx.x * blockDim.x + threadIdx.x;
    if (i >= 2 * n8) return;
    const float4* in4 = (const float4*)((i < n8) ? W1 : W2);
    int j = (i < n8) ? i : i - n8;
    float4 a = in4[2 * j], b = in4[2 * j + 1];
    uint4 o;
    o.x = (uint)f2bf(a.x) | ((uint)f2bf(a.y) << 16);
    o.y = (uint)f2bf(a.z) | ((uint)f2bf(a.w) << 16);
    o.z = (uint)f2bf(b.x) | ((uint)f2bf(b.y) << 16);
    o.w = (uint)f2bf(b.z) | ((uint)f2bf(b.w) << 16);
    ((uint4*)outp)[i] = o;
}

// h (bf16, >=0) -> h8 (fp8 e4m3 of h/8). 8 elems per thread.
__global__ void cast_h8(const ushort* __restrict__ h, uchar* __restrict__ h8, int n8) {
    int i = blockIdx.x * blockDim.x + threadIdx.x;
    if (i >= n8) return;
    uint4 v = ((const uint4*)h)[i];
    float f0 = fminf(bf_lo(v.x) * 0.125f, 448.f), f1 = fminf(bf_hi(v.x) * 0.125f, 448.f);
    float f2 = fminf(bf_lo(v.y) * 0.125f, 448.f), f3 = fminf(bf_hi(v.y) * 0.125f, 448.f);
    float f4 = fminf(bf_lo(v.z) * 0.125f, 448.f), f5 = fminf(bf_hi(v.z) * 0.125f, 448.f);
    float f6 = fminf(bf_lo(v.w) * 0.125f, 448.f), f7 = fminf(bf_hi(v.w) * 0.125f, 448.f);
    uint2 o;
    o.x = fp8_enc4(f0, f1, f2, f3);
    o.y = fp8_enc4(f4, f5, f6, f7);
    ((uint2*)h8)[i] = o;
}

// =======================================================================
// gemm_pairs (R11-proven): 256x128 tile, 512 thr (8 waves), direct LDS
// staging, slot^(r&7) swizzle. CAST0: pair0 A = f32 x, cast during stage,
// write-through xbout.
// =======================================================================

template<int RELU, int OUT_BF16, int CAST0>
__global__ __launch_bounds__(512)
void gemm_pairs(const void* __restrict__ A0, const ushort* __restrict__ W0,
                const ushort* __restrict__ A1, const ushort* __restrict__ W1p,
                int npairs, const int* __restrict__ deg, const float* __restrict__ cvec,
                void* __restrict__ Cout, ushort* __restrict__ xbout, int N)
{
    __shared__ uint4 A4[2048];   // 256 rows x 8 slots
    __shared__ uint4 W4[1024];   // 128 rows x 8 slots
    int t = threadIdx.x;
    int w = t >> 6, l = t & 63;
    int lg = l >> 4, lr = l & 15;
    int rowBase = blockIdx.x * 256;

    f32x4 acc[2][8];
#pragma unroll
    for (int rt = 0; rt < 2; ++rt)
#pragma unroll
        for (int ct = 0; ct < 8; ++ct) acc[rt][ct] = (f32x4){0.f, 0.f, 0.f, 0.f};

    for (int pr = 0; pr < npairs; ++pr) {
        const uint4* Ag = (const uint4*)(pr ? (const void*)A1 : A0);
        const uint4* Wg = (const uint4*)(pr ? W1p : W0);
        for (int kc = 0; kc < 2; ++kc) {
            if (pr || kc) __syncthreads();
#pragma unroll
            for (int it = 0; it < 4; ++it) {
                int idx = it * 512 + t;
                int r = idx >> 3, s = idx & 7;
                int gr = rowBase + r;
                uint4 v = make_uint4(0, 0, 0, 0);
                if (CAST0 && pr == 0) {
                    if (gr < N) {
                        const float4* xg = (const float4*)A0;
                        float4 a = xg[(size_t)gr * 32 + (kc * 8 + s) * 2];
                        float4 b = xg[(size_t)gr * 32 + (kc * 8 + s) * 2 + 1];
                        v.x = (uint)f2bf(a.x) | ((uint)f2bf(a.y) << 16);
                        v.y = (uint)f2bf(a.z) | ((uint)f2bf(a.w) << 16);
                        v.z = (uint)f2bf(b.x) | ((uint)f2bf(b.y) << 16);
                        v.w = (uint)f2bf(b.z) | ((uint)f2bf(b.w) << 16);
                        ((uint4*)xbout)[(size_t)gr * 16 + kc * 8 + s] = v;
                    }
                } else {
                    if (gr < N) v = Ag[(size_t)gr * 16 + kc * 8 + s];
                }
                A4[r * 8 + (s ^ (r & 7))] = v;
            }
#pragma unroll
            for (int it = 0; it < 2; ++it) {
                int idx = it * 512 + t;
                int r = idx >> 3, s = idx & 7;
                W4[r * 8 + (s ^ (r & 7))] = Wg[r * 16 + kc * 8 + s];
            }
            __syncthreads();
#pragma unroll
            for (int kk = 0; kk < 2; ++kk) {
                int slot = kk * 4 + lg;
                bf16x8 af[2], bfr[8];
#pragma unroll
                for (int rt = 0; rt < 2; ++rt) {
                    int r = w * 32 + rt * 16 + lr;
                    af[rt] = *(const bf16x8*)&A4[r * 8 + (slot ^ (r & 7))];
                }
#pragma unroll
                for (int ct = 0; ct < 8; ++ct) {
                    int r = ct * 16 + lr;
                    bfr[ct] = *(const bf16x8*)&W4[r * 8 + (slot ^ (r & 7))];
                }
#pragma unroll
                for (int rt = 0; rt < 2; ++rt)
#pragma unroll
                    for (int ct = 0; ct < 8; ++ct)
                        acc[rt][ct] = __builtin_amdgcn_mfma_f32_16x16x32_bf16(
                            af[rt], bfr[ct], acc[rt][ct], 0, 0, 0);
            }
        }
    }

    float cv[8];
#pragma unroll
    for (int ct = 0; ct < 8; ++ct) cv[ct] = cvec[ct * 16 + lr];
#pragma unroll
    for (int rt = 0; rt < 2; ++rt) {
#pragma unroll
        for (int j = 0; j < 4; ++j) {
            int gr = rowBase + w * 32 + rt * 16 + lg * 4 + j;
            if (gr < N) {
                float d = (float)deg[gr];
#pragma unroll
                for (int ct = 0; ct < 8; ++ct) {
                    int gc = ct * 16 + lr;
                    float v = acc[rt][ct][j] + d * cv[ct];
                    if (RELU) v = fmaxf(v, 0.f);
                    if (OUT_BF16) ((ushort*)Cout)[(size_t)gr * H + gc] = f2bf(v);
                    else ((float*)Cout)[(size_t)gr * H + gc] = v;
                }
            }
        }
    }
}

// =======================================================================
// aggregate_sum (bf16, measured floor ~61.5us): one wave per node,
// wave-uniform cols base, 8-deep gather unroll.
// =======================================================================

__global__ void aggregate_sum(const ushort* __restrict__ hsrc,
                              const int* __restrict__ off, const int* __restrict__ deg,
                              const int* __restrict__ cols,
                              ushort* __restrict__ sdst, int N)
{
    int node = blockIdx.x * 4 + (threadIdx.x >> 6);
    if (node >= N) return;
    int l = threadIdx.x & 63;
    int s = off[node], e = s + deg[node];
    const uint* pu = (const uint*)hsrc;  // [N][64]
    float ax = 0.f, ay = 0.f;
    int i = s;
    for (; i + 8 <= e; i += 8) {
        uint v0 = pu[(size_t)cols[i]     * 64 + l];
        uint v1 = pu[(size_t)cols[i + 1] * 64 + l];
        uint v2 = pu[(size_t)cols[i + 2] * 64 + l];
        uint v3 = pu[(size_t)cols[i + 3] * 64 + l];
        uint v4 = pu[(size_t)cols[i + 4] * 64 + l];
        uint v5 = pu[(size_t)cols[i + 5] * 64 + l];
        uint v6 = pu[(size_t)cols[i + 6] * 64 + l];
        uint v7 = pu[(size_t)cols[i + 7] * 64 + l];
        ax += bf_lo(v0) + bf_lo(v1) + bf_lo(v2) + bf_lo(v3)
            + bf_lo(v4) + bf_lo(v5) + bf_lo(v6) + bf_lo(v7);
        ay += bf_hi(v0) + bf_hi(v1) + bf_hi(v2) + bf_hi(v3)
            + bf_hi(v4) + bf_hi(v5) + bf_hi(v6) + bf_hi(v7);
    }
    for (; i + 4 <= e; i += 4) {
        uint v0 = pu[(size_t)cols[i]     * 64 + l];
        uint v1 = pu[(size_t)cols[i + 1] * 64 + l];
        uint v2 = pu[(size_t)cols[i + 2] * 64 + l];
        uint v3 = pu[(size_t)cols[i + 3] * 64 + l];
        ax += bf_lo(v0) + bf_lo(v1) + bf_lo(v2) + bf_lo(v3);
        ay += bf_hi(v0) + bf_hi(v1) + bf_hi(v2) + bf_hi(v3);
    }
    for (; i < e; ++i) {
        uint v = pu[(size_t)cols[i] * 64 + l];
        ax += bf_lo(v);
        ay += bf_hi(v);
    }
    ((uint*)sdst)[(size_t)node * 64 + l] = (uint)f2bf(ax) | ((uint)f2bf(ay) << 16);
}

// =======================================================================
// aggregate_fp8: same structure, gathers h8 (fp8 of h/8), lane reads a
// ushort (2 fp8 = cols 2l,2l+1), dequant x8 at the end. Halves L2 fill.
// =======================================================================

__global__ void aggregate_fp8(const uchar* __restrict__ h8,
                              const int* __restrict__ off, const int* __restrict__ deg,
                              const int* __restrict__ cols,
                              ushort* __restrict__ sdst, int N)
{
    int node = blockIdx.x * 4 + (threadIdx.x >> 6);
    if (node >= N) return;
    int l = threadIdx.x & 63;
    int s = off[node], e = s + deg[node];
    const ushort* pu = (const ushort*)h8;   // [N][64] (2 fp8 per ushort)
    float ax = 0.f, ay = 0.f;
    int i = s;
    for (; i + 8 <= e; i += 8) {
        uint v0 = pu[(size_t)cols[i]     * 64 + l];
        uint v1 = pu[(size_t)cols[i + 1] * 64 + l];
        uint v2 = pu[(size_t)cols[i + 2] * 64 + l];
        uint v3 = pu[(size_t)cols[i + 3] * 64 + l];
        uint v4 = pu[(size_t)cols[i + 4] * 64 + l];
        uint v5 = pu[(size_t)cols[i + 5] * 64 + l];
        uint v6 = pu[(size_t)cols[i + 6] * 64 + l];
        uint v7 = pu[(size_t)cols[i + 7] * 64 + l];
        float2 f0 = fp8_dec2(v0), f1 = fp8_dec2(v1), f2 = fp8_dec2(v2), f3 = fp8_dec2(v3);
        float2 f4 = fp8_dec2(v4), f5 = fp8_dec2(v5), f6 = fp8_dec2(v6), f7 = fp8_dec2(v7);
        ax += f0.x + f1.x + f2.x + f3.x + f4.x + f5.x + f6.x + f7.x;
        ay += f0.y + f1.y + f2.y + f3.y + f4.y + f5.y + f6.y + f7.y;
    }
    for (; i < e; ++i) {
        float2 f = fp8_dec2(pu[(size_t)cols[i] * 64 + l]);
        ax += f.x;
        ay += f.y;
    }
    ax *= 8.f;
    ay *= 8.f;
    ((uint*)sdst)[(size_t)node * 64 + l] = (uint)f2bf(ax) | ((uint)f2bf(ay) << 16);
}

// =======================================================================
// launch
// =======================================================================

extern "C" void kernel_launch(void* const* d_in, const int* in_sizes, int n_in,
                              void* d_out, int out_size, void* d_ws, size_t ws_size,
                              hipStream_t stream)
{
    const float* x  = (const float*)d_in[0];
    const int*   ei = (const int*)d_in[1];
    const float* W1 = (const float*)d_in[2];
    const float* W2 = (const float*)d_in[3];
    const float* W3 = (const float*)d_in[4];
    const float* W4 = (const float*)d_in[5];
    int N   = in_sizes[0] / H;
    int E   = in_sizes[1] / 2;
    int HOP = in_sizes[2] / (H * H);

    int NB   = (N + BROWS - 1) >> BSH;
    int NBLK = (E + 4095) >> 12;

    char* ws = (char*)d_ws;
    int*   gcnt  = (int*)ws;                  // NB*16 (line-padded)
    int*   deg   = gcnt + NB * 16;            // N
    int*   off   = deg + N;                   // N
    int*   colss = off + N;                   // NB*BCAP
    float* cvec  = (float*)(colss + (size_t)NB * BCAP);   // HOP*H
    size_t fo = (((size_t)((char*)(cvec + HOP * H) - ws)) + 255) & ~(size_t)255;
    int2*  ebuf  = (int2*)(ws + fo);          // NB*BCAP int2
    ushort* W1b  = (ushort*)(ebuf + (size_t)NB * BCAP);   // HOP*H*H
    ushort* W2b  = W1b + (size_t)HOP * H * H; // HOP*H*H (contiguous)
    ushort* xb   = W2b + (size_t)HOP * H * H; // N*H
    ushort* h    = xb + (size_t)N * H;        // N*H
    ushort* sagg = h + (size_t)N * H;         // N*H
    uchar*  h8   = (uchar*)(sagg + (size_t)N * H);        // N*H bytes

    // ---- CSR build ----
    hipMemsetAsync(gcnt, 0, sizeof(int) * NB * 16, stream);
    scatter_direct<<<NBLK, 256, 0, stream>>>(ei, E, NB, gcnt, ebuf);
    bucket_csr2<<<NB, 1024, 0, stream>>>(ebuf, gcnt, NB, N, deg, off, colss);

    cvec_kernel<<<HOP, 256, 0, stream>>>(W3, W4, cvec);

    int nw8 = HOP * H * H / 8;
    cast_w<<<(2 * nw8 + 255) / 256, 256, 0, stream>>>(W1, W2, W1b, nw8);

    int gblocks = (N + 255) / 256;
    float* out = (float*)d_out;

    // hop 0: h = relu(x@W1[0]^T + deg*c0), fused f32->bf16 cast writes xb
    if (HOP == 1) {
        gemm_pairs<1, 0, 1><<<gblocks, 512, 0, stream>>>(x, W1b, nullptr, nullptr, 1,
                                                         deg, cvec, out, xb, N);
        return;
    }
    gemm_pairs<1, 1, 1><<<gblocks, 512, 0, stream>>>(x, W1b, nullptr, nullptr, 1,
                                                     deg, cvec, h, xb, N);

    int nh8 = N * H / 8;
    for (int i = 1; i < HOP; ++i) {
        int last = (i == HOP - 1);
        // sagg = A . h   -- hop 1 via fp8 (A/B probe), later hops bf16
        if (i == 1) {
            cast_h8<<<(nh8 + 255) / 256, 256, 0, stream>>>(h, h8, nh8);
            aggregate_fp8<<<(N + 3) / 4, 256, 0, stream>>>(h8, off, deg, colss, sagg, N);
        } else {
            aggregate_sum<<<(N + 3) / 4, 256, 0, stream>>>(h, off, deg, colss, sagg, N);
        }
        // dst = relu(xb@W1[i]^T + sagg@W2[i]^T + deg*c_i)
        if (last)
            gemm_pairs<1, 0, 0><<<gblocks, 512, 0, stream>>>(xb, W1b + (size_t)i * H * H,
                                                             sagg, W2b + (size_t)i * H * H,
                                                             2, deg, cvec + i * H, out,
                                                             nullptr, N);
        else
            gemm_pairs<1, 1, 0><<<gblocks, 512, 0, stream>>>(xb, W1b + (size_t)i * H * H,
                                                             sagg, W2b + (size_t)i * H * H,
                                                             2, deg, cvec + i * H, h,
                                                             nullptr, N);
    }
}

// Round 15
// 259.501 us; speedup vs baseline: 1.0982x; 1.0982x over previous
//
#include <hip/hip_runtime.h>

#define H 128
#define BSH 10                // bucket shift: 1024 rows per bucket
#define BROWS (1 << BSH)
#define BCAP 18432            // per-bucket edge cap (mean 16384 + ~16 sigma)

typedef __attribute__((ext_vector_type(8))) short bf16x8;
typedef __attribute__((ext_vector_type(4))) float f32x4;
typedef unsigned int uint;
typedef unsigned short ushort;

__device__ __forceinline__ ushort f2bf(float f) {
    uint u = __builtin_bit_cast(uint, f);
    uint r = u + 0x7FFFu + ((u >> 16) & 1u);
    return (ushort)(r >> 16);
}
__device__ __forceinline__ float bf_lo(uint u) {
    return __builtin_bit_cast(float, u << 16);
}
__device__ __forceinline__ float bf_hi(uint u) {
    return __builtin_bit_cast(float, u & 0xFFFF0000u);
}

// =======================================================================
// CSR build: fixed-capacity 1024-row buckets (R11-proven), 2 kernels.
// =======================================================================

__global__ void scatter_direct(const int* __restrict__ ei, int E, int NB,
                               int* __restrict__ gcnt, int2* __restrict__ ebuf) {
    __shared__ int cnt[1024];
    __shared__ int base[1024];
    int blk = blockIdx.x, t = threadIdx.x;
    for (int b = t; b < NB; b += 256) cnt[b] = 0;
    __syncthreads();
    int lo = blk << 12, hi = min(lo + 4096, E);
    for (int e = lo + t; e < hi; e += 256) atomicAdd(&cnt[ei[e] >> BSH], 1);
    __syncthreads();
    for (int b = t; b < NB; b += 256) {
        int c = cnt[b];
        base[b] = c ? atomicAdd(&gcnt[b * 16], c) : 0;
        cnt[b] = 0;
    }
    __syncthreads();
    for (int e = lo + t; e < hi; e += 256) {
        int r = ei[e], c = ei[E + e];
        int b = r >> BSH;
        int pos = base[b] + atomicAdd(&cnt[b], 1);
        if (pos < BCAP) ebuf[(size_t)b * BCAP + pos] = make_int2(r, c);
    }
}

__global__ __launch_bounds__(1024)
void bucket_csr2(const int2* __restrict__ ebuf, const int* __restrict__ gcnt,
                 int NB, int N, int* __restrict__ deg, int* __restrict__ off,
                 int* __restrict__ colss) {
    __shared__ int rcnt[BROWS], rloff[BROWS];
    int b = blockIdx.x, t = threadIdx.x;
    int rowbase = b << BSH;
    int ebase = b * BCAP;
    int ne = min(gcnt[b * 16], BCAP);
    rcnt[t] = 0;
    __syncthreads();
    for (int e = t; e < ne; e += 1024) atomicAdd(&rcnt[ebuf[(size_t)ebase + e].x - rowbase], 1);
    __syncthreads();
    int v = rcnt[t];
    rloff[t] = v;
    __syncthreads();
    for (int d = 1; d < BROWS; d <<= 1) {
        int u = (t >= d) ? rloff[t - d] : 0;
        __syncthreads();
        rloff[t] += u;
        __syncthreads();
    }
    int ex = rloff[t] - v;
    int row = rowbase + t;
    if (row < N) {
        deg[row] = v;
        off[row] = ebase + ex;
    }
    __syncthreads();
    rloff[t] = ex;
    rcnt[t] = 0;
    __syncthreads();
    for (int e = t; e < ne; e += 1024) {
        int2 rc = ebuf[(size_t)ebase + e];
        int lr = rc.x - rowbase;
        int pz = atomicAdd(&rcnt[lr], 1);
        colss[ebase + rloff[lr] + pz] = rc.y;
    }
}

// =======================================================================
// prep_kernel: one launch doing (a) weight bf16 casts, (b) cvec, (c) gcnt
// zero-init. Role selected by blockIdx.
//   blocks [0, castB)          : cast W1,W2 -> W1b,W2b (contiguous dst)
//   blocks [castB, castB+HOP)  : cvec hop (i = blk - castB), one wave/k
//   block  castB+HOP           : zero gcnt[NB*16]
// =======================================================================

__global__ void prep_kernel(const float* __restrict__ W1, const float* __restrict__ W2,
                            ushort* __restrict__ wout, int n8,
                            const float* __restrict__ W3, const float* __restrict__ W4,
                            float* __restrict__ cvec, int castB, int HOP,
                            int* __restrict__ gcnt, int NB)
{
    int blk = blockIdx.x, t = threadIdx.x;
    if (blk < castB) {
        int i = blk * 256 + t;
        if (i < 2 * n8) {
            const float4* in4 = (const float4*)((i < n8) ? W1 : W2);
            int j = (i < n8) ? i : i - n8;
            float4 a = in4[2 * j], b = in4[2 * j + 1];
            uint4 o;
            o.x = (uint)f2bf(a.x) | ((uint)f2bf(a.y) << 16);
            o.y = (uint)f2bf(a.z) | ((uint)f2bf(a.w) << 16);
            o.z = (uint)f2bf(b.x) | ((uint)f2bf(b.y) << 16);
            o.w = (uint)f2bf(b.z) | ((uint)f2bf(b.w) << 16);
            ((uint4*)wout)[i] = o;
        }
        return;
    }
    if (blk < castB + HOP) {
        int i = blk - castB;
        __shared__ float r4[H];
        if (t < H) r4[t] = fmaxf(W4[i * H + t], 0.f);
        __syncthreads();
        int wv = t >> 6, l = t & 63;
        for (int k = wv; k < H; k += 4) {
            const float* w3 = W3 + (size_t)i * H * H + (size_t)k * H;
            float s = w3[l] * r4[l] + w3[l + 64] * r4[l + 64];
            for (int d = 1; d < 64; d <<= 1) s += __shfl_xor(s, d);
            if (l == 0) cvec[i * H + k] = s;
        }
        return;
    }
    for (int i = t; i < NB * 16; i += 256) gcnt[i] = 0;
}

// =======================================================================
// gemm_pairs (R11-proven): 256x128 tile, 512 thr (8 waves), direct LDS
// staging, slot^(r&7) swizzle. CAST0: pair0 A = f32 x, cast during stage,
// write-through xbout.
// =======================================================================

template<int RELU, int OUT_BF16, int CAST0>
__global__ __launch_bounds__(512)
void gemm_pairs(const void* __restrict__ A0, const ushort* __restrict__ W0,
                const ushort* __restrict__ A1, const ushort* __restrict__ W1p,
                int npairs, const int* __restrict__ deg, const float* __restrict__ cvec,
                void* __restrict__ Cout, ushort* __restrict__ xbout, int N)
{
    __shared__ uint4 A4[2048];   // 256 rows x 8 slots
    __shared__ uint4 W4[1024];   // 128 rows x 8 slots
    int t = threadIdx.x;
    int w = t >> 6, l = t & 63;
    int lg = l >> 4, lr = l & 15;
    int rowBase = blockIdx.x * 256;

    f32x4 acc[2][8];
#pragma unroll
    for (int rt = 0; rt < 2; ++rt)
#pragma unroll
        for (int ct = 0; ct < 8; ++ct) acc[rt][ct] = (f32x4){0.f, 0.f, 0.f, 0.f};

    for (int pr = 0; pr < npairs; ++pr) {
        const uint4* Ag = (const uint4*)(pr ? (const void*)A1 : A0);
        const uint4* Wg = (const uint4*)(pr ? W1p : W0);
        for (int kc = 0; kc < 2; ++kc) {
            if (pr || kc) __syncthreads();
#pragma unroll
            for (int it = 0; it < 4; ++it) {
                int idx = it * 512 + t;
                int r = idx >> 3, s = idx & 7;
                int gr = rowBase + r;
                uint4 v = make_uint4(0, 0, 0, 0);
                if (CAST0 && pr == 0) {
                    if (gr < N) {
                        const float4* xg = (const float4*)A0;
                        float4 a = xg[(size_t)gr * 32 + (kc * 8 + s) * 2];
                        float4 b = xg[(size_t)gr * 32 + (kc * 8 + s) * 2 + 1];
                        v.x = (uint)f2bf(a.x) | ((uint)f2bf(a.y) << 16);
                        v.y = (uint)f2bf(a.z) | ((uint)f2bf(a.w) << 16);
                        v.z = (uint)f2bf(b.x) | ((uint)f2bf(b.y) << 16);
                        v.w = (uint)f2bf(b.z) | ((uint)f2bf(b.w) << 16);
                        ((uint4*)xbout)[(size_t)gr * 16 + kc * 8 + s] = v;
                    }
                } else {
                    if (gr < N) v = Ag[(size_t)gr * 16 + kc * 8 + s];
                }
                A4[r * 8 + (s ^ (r & 7))] = v;
            }
#pragma unroll
            for (int it = 0; it < 2; ++it) {
                int idx = it * 512 + t;
                int r = idx >> 3, s = idx & 7;
                W4[r * 8 + (s ^ (r & 7))] = Wg[r * 16 + kc * 8 + s];
            }
            __syncthreads();
#pragma unroll
            for (int kk = 0; kk < 2; ++kk) {
                int slot = kk * 4 + lg;
                bf16x8 af[2], bfr[8];
#pragma unroll
                for (int rt = 0; rt < 2; ++rt) {
                    int r = w * 32 + rt * 16 + lr;
                    af[rt] = *(const bf16x8*)&A4[r * 8 + (slot ^ (r & 7))];
                }
#pragma unroll
                for (int ct = 0; ct < 8; ++ct) {
                    int r = ct * 16 + lr;
                    bfr[ct] = *(const bf16x8*)&W4[r * 8 + (slot ^ (r & 7))];
                }
#pragma unroll
                for (int rt = 0; rt < 2; ++rt)
#pragma unroll
                    for (int ct = 0; ct < 8; ++ct)
                        acc[rt][ct] = __builtin_amdgcn_mfma_f32_16x16x32_bf16(
                            af[rt], bfr[ct], acc[rt][ct], 0, 0, 0);
            }
        }
    }

    float cv[8];
#pragma unroll
    for (int ct = 0; ct < 8; ++ct) cv[ct] = cvec[ct * 16 + lr];
#pragma unroll
    for (int rt = 0; rt < 2; ++rt) {
#pragma unroll
        for (int j = 0; j < 4; ++j) {
            int gr = rowBase + w * 32 + rt * 16 + lg * 4 + j;
            if (gr < N) {
                float d = (float)deg[gr];
#pragma unroll
                for (int ct = 0; ct < 8; ++ct) {
                    int gc = ct * 16 + lr;
                    float v = acc[rt][ct][j] + d * cv[ct];
                    if (RELU) v = fmaxf(v, 0.f);
                    if (OUT_BF16) ((ushort*)Cout)[(size_t)gr * H + gc] = f2bf(v);
                    else ((float*)Cout)[(size_t)gr * H + gc] = v;
                }
            }
        }
    }
}

// =======================================================================
// aggregate_sum (measured floor ~61.5us, access-count-bound): one wave
// per node, wave-uniform cols base, 8-deep gather unroll.
// =======================================================================

__global__ void aggregate_sum(const ushort* __restrict__ hsrc,
                              const int* __restrict__ off, const int* __restrict__ deg,
                              const int* __restrict__ cols,
                              ushort* __restrict__ sdst, int N)
{
    int node = blockIdx.x * 4 + (threadIdx.x >> 6);
    if (node >= N) return;
    int l = threadIdx.x & 63;
    int s = off[node], e = s + deg[node];
    const uint* pu = (const uint*)hsrc;  // [N][64]
    float ax = 0.f, ay = 0.f;
    int i = s;
    for (; i + 8 <= e; i += 8) {
        uint v0 = pu[(size_t)cols[i]     * 64 + l];
        uint v1 = pu[(size_t)cols[i + 1] * 64 + l];
        uint v2 = pu[(size_t)cols[i + 2] * 64 + l];
        uint v3 = pu[(size_t)cols[i + 3] * 64 + l];
        uint v4 = pu[(size_t)cols[i + 4] * 64 + l];
        uint v5 = pu[(size_t)cols[i + 5] * 64 + l];
        uint v6 = pu[(size_t)cols[i + 6] * 64 + l];
        uint v7 = pu[(size_t)cols[i + 7] * 64 + l];
        ax += bf_lo(v0) + bf_lo(v1) + bf_lo(v2) + bf_lo(v3)
            + bf_lo(v4) + bf_lo(v5) + bf_lo(v6) + bf_lo(v7);
        ay += bf_hi(v0) + bf_hi(v1) + bf_hi(v2) + bf_hi(v3)
            + bf_hi(v4) + bf_hi(v5) + bf_hi(v6) + bf_hi(v7);
    }
    for (; i + 4 <= e; i += 4) {
        uint v0 = pu[(size_t)cols[i]     * 64 + l];
        uint v1 = pu[(size_t)cols[i + 1] * 64 + l];
        uint v2 = pu[(size_t)cols[i + 2] * 64 + l];
        uint v3 = pu[(size_t)cols[i + 3] * 64 + l];
        ax += bf_lo(v0) + bf_lo(v1) + bf_lo(v2) + bf_lo(v3);
        ay += bf_hi(v0) + bf_hi(v1) + bf_hi(v2) + bf_hi(v3);
    }
    for (; i < e; ++i) {
        uint v = pu[(size_t)cols[i] * 64 + l];
        ax += bf_lo(v);
        ay += bf_hi(v);
    }
    ((uint*)sdst)[(size_t)node * 64 + l] = (uint)f2bf(ax) | ((uint)f2bf(ay) << 16);
}

// =======================================================================
// launch
// =======================================================================

extern "C" void kernel_launch(void* const* d_in, const int* in_sizes, int n_in,
                              void* d_out, int out_size, void* d_ws, size_t ws_size,
                              hipStream_t stream)
{
    const float* x  = (const float*)d_in[0];
    const int*   ei = (const int*)d_in[1];
    const float* W1 = (const float*)d_in[2];
    const float* W2 = (const float*)d_in[3];
    const float* W3 = (const float*)d_in[4];
    const float* W4 = (const float*)d_in[5];
    int N   = in_sizes[0] / H;
    int E   = in_sizes[1] / 2;
    int HOP = in_sizes[2] / (H * H);

    int NB   = (N + BROWS - 1) >> BSH;
    int NBLK = (E + 4095) >> 12;

    char* ws = (char*)d_ws;
    int*   gcnt  = (int*)ws;                  // NB*16 (line-padded)
    int*   deg   = gcnt + NB * 16;            // N
    int*   off   = deg + N;                   // N
    int*   colss = off + N;                   // NB*BCAP
    float* cvec  = (float*)(colss + (size_t)NB * BCAP);   // HOP*H
    size_t fo = (((size_t)((char*)(cvec + HOP * H) - ws)) + 255) & ~(size_t)255;
    int2*  ebuf  = (int2*)(ws + fo);          // NB*BCAP int2
    ushort* W1b  = (ushort*)(ebuf + (size_t)NB * BCAP);   // HOP*H*H
    ushort* W2b  = W1b + (size_t)HOP * H * H; // HOP*H*H (contiguous)
    ushort* xb   = W2b + (size_t)HOP * H * H; // N*H
    ushort* h    = xb + (size_t)N * H;        // N*H
    ushort* sagg = h + (size_t)N * H;         // N*H

    // ---- prep: weight casts + cvec + gcnt zero (one launch) ----
    int nw8 = HOP * H * H / 8;
    int castB = (2 * nw8 + 255) / 256;
    prep_kernel<<<castB + HOP + 1, 256, 0, stream>>>(W1, W2, W1b, nw8,
                                                     W3, W4, cvec, castB, HOP,
                                                     gcnt, NB);

    // ---- CSR build ----
    scatter_direct<<<NBLK, 256, 0, stream>>>(ei, E, NB, gcnt, ebuf);
    bucket_csr2<<<NB, 1024, 0, stream>>>(ebuf, gcnt, NB, N, deg, off, colss);

    int gblocks = (N + 255) / 256;
    float* out = (float*)d_out;

    // hop 0: h = relu(x@W1[0]^T + deg*c0), fused f32->bf16 cast writes xb
    if (HOP == 1) {
        gemm_pairs<1, 0, 1><<<gblocks, 512, 0, stream>>>(x, W1b, nullptr, nullptr, 1,
                                                         deg, cvec, out, xb, N);
        return;
    }
    gemm_pairs<1, 1, 1><<<gblocks, 512, 0, stream>>>(x, W1b, nullptr, nullptr, 1,
                                                     deg, cvec, h, xb, N);

    for (int i = 1; i < HOP; ++i) {
        int last = (i == HOP - 1);
        // sagg = A . h
        aggregate_sum<<<(N + 3) / 4, 256, 0, stream>>>(h, off, deg, colss, sagg, N);
        // dst = relu(xb@W1[i]^T + sagg@W2[i]^T + deg*c_i)
        if (last)
            gemm_pairs<1, 0, 0><<<gblocks, 512, 0, stream>>>(xb, W1b + (size_t)i * H * H,
                                                             sagg, W2b + (size_t)i * H * H,
                                                             2, deg, cvec + i * H, out,
                                                             nullptr, N);
        else
            gemm_pairs<1, 1, 0><<<gblocks, 512, 0, stream>>>(xb, W1b + (size_t)i * H * H,
                                                             sagg, W2b + (size_t)i * H * H,
                                                             2, deg, cvec + i * H, h,
                                                             nullptr, N);
    }
}